// Round 4
// baseline (85.247 us; speedup 1.0000x reference)
//
#include <hip/hip_runtime.h>

#define NK3 30  // 3*K columns per node
#define NKP 15  // float2 pairs per row

__device__ __forceinline__ float hw_log2(float a) { return __builtin_amdgcn_logf(a); }
__device__ __forceinline__ float hw_exp2(float a) { return __builtin_amdgcn_exp2f(a); }

// ---------------- K1: balanced flat accumulation ----------------
// 128 nodes per wave. Lane layout: nodesub = lane>>4 (4 nodes/step),
// cp = lane&15 (15 active float2 column-pairs). Each lane serially
// accumulates exp2(xe - t) for its 2 columns; segment boundary -> atomicAdd
// flush into wsum[seg*30+col]. No shuffles, no LDS, ~1 live acc pair.
__global__ __launch_bounds__(256) void k1_accumulate(
    const float* __restrict__ x, const float* __restrict__ uniforms,
    const int* __restrict__ ptr, float* __restrict__ wsum, int N, int B)
{
    const int wid  = (blockIdx.x << 2) + (threadIdx.x >> 6);
    const int lane = threadIdx.x & 63;
    const int nodesub = lane >> 4;
    const int cp      = lane & 15;
    const bool active = cp < NKP;

    const int base = wid << 7;  // 128 nodes / wave
    if (base >= N) return;

    int n0 = base + nodesub;
    int lo = 0, hi = B;  // largest seg with ptr[seg] <= n0
    while (hi - lo > 1) { int mid = (lo + hi) >> 1; if (ptr[mid] <= n0) lo = mid; else hi = mid; }
    int seg = lo;
    int ptr_next = ptr[seg + 1];

    float ax = 0.f, ay = 0.f;

    for (int s = 0; s < 32; ++s) {
        const int n = base + (s << 2) + nodesub;
        if (n < N) {
            if (n >= ptr_next) {  // crossed into a new segment: flush old acc
                if (active) {
                    atomicAdd(&wsum[seg * NK3 + (cp << 1)    ], ax);
                    atomicAdd(&wsum[seg * NK3 + (cp << 1) + 1], ay);
                }
                ax = 0.f; ay = 0.f;
                do { ++seg; ptr_next = ptr[seg + 1]; } while (n >= ptr_next);
            }
            if (active) {
                const float xe = fmaf(x[n], 1.44269504f, 0.52876637f);
                const float2 u =
                    reinterpret_cast<const float2*>(uniforms + (size_t)n * NK3)[cp];
                const float t0 = hw_log2(-hw_log2(u.x));
                const float t1 = hw_log2(-hw_log2(u.y));
                ax += hw_exp2(xe - t0);
                ay += hw_exp2(xe - t1);
            }
        }
    }
    if (active) {
        atomicAdd(&wsum[seg * NK3 + (cp << 1)    ], ax);
        atomicAdd(&wsum[seg * NK3 + (cp << 1) + 1], ay);
    }
}

// ---------------- K2: lw = log2(denom), in place ----------------
__global__ __launch_bounds__(256) void k2_log(float* __restrict__ wsum, int count)
{
    const int i = blockIdx.x * 256 + threadIdx.x;
    if (i < count) wsum[i] = hw_log2(wsum[i]);
}

// ---------------- K3: out[n] = exp2(xe - min_j (t_j + lw_j)) ----------------
// 256 nodes per wave (4 chunks of 64), row-per-lane, uniforms re-read L3-hot.
__global__ __launch_bounds__(256) void k3_output(
    const float* __restrict__ x, const float* __restrict__ uniforms,
    const int* __restrict__ ptr, const float* __restrict__ lw,
    float* __restrict__ out, int N, int B)
{
    const int wid  = (blockIdx.x << 2) + (threadIdx.x >> 6);
    const int lane = threadIdx.x & 63;
    const int base = wid << 8;  // 256 nodes / wave
    if (base >= N) return;

    const int n0 = base + lane;
    int lo = 0, hi = B;
    while (hi - lo > 1) { int mid = (lo + hi) >> 1; if (ptr[mid] <= n0) lo = mid; else hi = mid; }
    int seg = lo;

    for (int c = 0; c < 4; ++c) {
        const int n = base + (c << 6) + lane;
        if (n >= N) return;
        while (n >= ptr[seg + 1]) ++seg;  // monotone advance, L1-hot

        float l[NK3];
#pragma unroll
        for (int j = 0; j < NK3; ++j) l[j] = lw[seg * NK3 + j];

        const float2* row = reinterpret_cast<const float2*>(uniforms + (size_t)n * NK3);
        float mn = 3.0e38f;
#pragma unroll
        for (int k = 0; k < NKP; ++k) {
            const float2 u = row[k];
            const float t0 = hw_log2(-hw_log2(u.x));
            const float t1 = hw_log2(-hw_log2(u.y));
            mn = fminf(mn, fminf(t0 + l[2 * k], t1 + l[2 * k + 1]));
        }
        out[n] = hw_exp2(fmaf(x[n], 1.44269504f, 0.52876637f) - mn);
    }
}

// ---------------- Fallback: round-3 single kernel (if ws too small) ----------------
__global__ __launch_bounds__(256) void gnn_fallback(
    const float* __restrict__ x, const float* __restrict__ uniforms,
    const int* __restrict__ ptr, float* __restrict__ out)
{
    const int wave = threadIdx.x >> 6;
    const int lane = threadIdx.x & 63;
    const int g = (blockIdx.x << 2) + wave;
    const int start = ptr[g];
    const int end   = ptr[g + 1];
    if (end <= start) return;

    float acc[NK3];
#pragma unroll
    for (int j = 0; j < NK3; ++j) acc[j] = 0.0f;
    const int iters = (end - start + 63) >> 6;

    for (int it = 0; it < iters; ++it) {
        const int n = start + (it << 6) + lane;
        if (n < end) {
            const float xe = fmaf(x[n], 1.44269504f, 0.52876637f);
            const float2* row = reinterpret_cast<const float2*>(uniforms + (size_t)n * NK3);
#pragma unroll
            for (int k = 0; k < NKP; ++k) {
                float2 u = row[k];
                float t0 = hw_log2(-hw_log2(u.x));
                float t1 = hw_log2(-hw_log2(u.y));
                acc[2 * k]     += hw_exp2(xe - t0);
                acc[2 * k + 1] += hw_exp2(xe - t1);
            }
        }
    }
#pragma unroll
    for (int j = 0; j < NK3; ++j) {
        float v = acc[j];
#pragma unroll
        for (int off = 1; off < 64; off <<= 1) v += __shfl_xor(v, off, 64);
        acc[j] = hw_log2(v);
    }
    for (int it = 0; it < iters; ++it) {
        const int n = start + (it << 6) + lane;
        if (n < end) {
            const float xe = fmaf(x[n], 1.44269504f, 0.52876637f);
            const float2* row = reinterpret_cast<const float2*>(uniforms + (size_t)n * NK3);
            float mn = 3.0e38f;
#pragma unroll
            for (int k = 0; k < NKP; ++k) {
                float2 u = row[k];
                float t0 = hw_log2(-hw_log2(u.x));
                float t1 = hw_log2(-hw_log2(u.y));
                mn = fminf(mn, fminf(t0 + acc[2 * k], t1 + acc[2 * k + 1]));
            }
            out[n] = hw_exp2(xe - mn);
        }
    }
}

extern "C" void kernel_launch(void* const* d_in, const int* in_sizes, int n_in,
                              void* d_out, int out_size, void* d_ws, size_t ws_size,
                              hipStream_t stream) {
    const float* x        = (const float*)d_in[0];
    const float* uniforms = (const float*)d_in[1];
    const int*   ptr      = (const int*)d_in[2];
    float* out = (float*)d_out;

    const int N = in_sizes[0];
    const int B = in_sizes[2] - 1;
    const size_t ws_needed = (size_t)B * NK3 * sizeof(float);

    if (ws_size >= ws_needed && d_ws != nullptr) {
        float* wsum = (float*)d_ws;
        hipMemsetAsync(wsum, 0, ws_needed, stream);

        const int b1 = (N + 511) / 512;           // 4 waves x 128 nodes
        k1_accumulate<<<b1, 256, 0, stream>>>(x, uniforms, ptr, wsum, N, B);

        const int cnt = B * NK3;
        const int b2 = (cnt + 255) / 256;
        k2_log<<<b2, 256, 0, stream>>>(wsum, cnt);

        const int b3 = (N + 1023) / 1024;         // 4 waves x 256 nodes
        k3_output<<<b3, 256, 0, stream>>>(x, uniforms, ptr, wsum, out, N, B);
    } else {
        const int blocks = (B + 3) / 4;
        gnn_fallback<<<blocks, 256, 0, stream>>>(x, uniforms, ptr, out);
    }
}

// Round 5
// 81.457 us; speedup vs baseline: 1.0465x; 1.0465x over previous
//
#include <hip/hip_runtime.h>

#define NK3 30  // 3*K columns per node
#define NKP 15  // float2 pairs per row

__device__ __forceinline__ float hw_log2(float a) { return __builtin_amdgcn_logf(a); }
__device__ __forceinline__ float hw_exp2(float a) { return __builtin_amdgcn_exp2f(a); }
__device__ __forceinline__ float hw_rcp(float a)  { return __builtin_amdgcn_rcpf(a); }

// Math: e_nj = exp(x_n + gumbel_nj) = exp(x_n) * 1/(-ln u_nj)
//            = exp2(x_n*log2e) * rcp(-log2 u_nj) * (1/ln2)   [1/ln2 cancels in ratio]
// We store denom' = sum_n exp2(xe_n)*rcp(w_nj), out = exp2(xe)*max_j(r_j * rcp(denom'_j)).

// ---------------- K1: balanced flat accumulation, deep-MLP ----------------
// 128 nodes per wave. Lane layout: nodesub = lane>>4, cp = lane&15 (15 active
// float2 column-pairs). 4 supersteps x 32 nodes: batch 16 independent loads
// into registers first (MLP=16), then branchy segment tracking on registers.
__global__ __launch_bounds__(256) void k1_accumulate(
    const float* __restrict__ x, const float* __restrict__ uniforms,
    const int* __restrict__ ptr, float* __restrict__ wsum, int N, int B)
{
    const int wid  = (blockIdx.x << 2) + (threadIdx.x >> 6);
    const int lane = threadIdx.x & 63;
    const int nodesub = lane >> 4;
    const int cp      = lane & 15;
    const bool active = cp < NKP;
    const int cpl     = active ? cp : 0;   // keep inactive lanes' loads in-bounds

    const int base = wid << 7;  // 128 nodes / wave
    if (base >= N) return;

    const int n0 = base + nodesub;
    int lo = 0, hi = B;  // largest seg with ptr[seg] <= n0
    while (hi - lo > 1) { int mid = (lo + hi) >> 1; if (ptr[mid] <= n0) lo = mid; else hi = mid; }
    int seg = lo;
    int ptr_next = ptr[seg + 1];

    float ax = 0.f, ay = 0.f;

    for (int s8 = 0; s8 < 4; ++s8) {
        float2 u[8];
        float  xv[8];
#pragma unroll
        for (int q = 0; q < 8; ++q) {
            const int n = base + (s8 << 5) + (q << 2) + nodesub;
            const int nc = (n < N) ? n : (N - 1);
            u[q]  = reinterpret_cast<const float2*>(uniforms + (size_t)nc * NK3)[cpl];
            xv[q] = x[nc];
        }
#pragma unroll
        for (int q = 0; q < 8; ++q) {
            const int n = base + (s8 << 5) + (q << 2) + nodesub;
            if (n < N) {
                if (n >= ptr_next) {  // crossed into new segment: flush old acc
                    if (active) {
                        atomicAdd(&wsum[seg * NK3 + (cp << 1)    ], ax);
                        atomicAdd(&wsum[seg * NK3 + (cp << 1) + 1], ay);
                    }
                    ax = 0.f; ay = 0.f;
                    do { ++seg; ptr_next = ptr[seg + 1]; } while (n >= ptr_next);
                }
                const float E  = hw_exp2(xv[q] * 1.44269504f);
                const float w0 = -hw_log2(u[q].x);
                const float w1 = -hw_log2(u[q].y);
                ax = fmaf(E, hw_rcp(w0), ax);
                ay = fmaf(E, hw_rcp(w1), ay);
            }
        }
    }
    if (active) {
        atomicAdd(&wsum[seg * NK3 + (cp << 1)    ], ax);
        atomicAdd(&wsum[seg * NK3 + (cp << 1) + 1], ay);
    }
}

// ---------------- K2: rd = rcp(denom'), in place ----------------
__global__ __launch_bounds__(256) void k2_rcp(float* __restrict__ wsum, int count)
{
    const int i = blockIdx.x * 256 + threadIdx.x;
    if (i < count) wsum[i] = hw_rcp(wsum[i]);
}

// ---------------- K3: out[n] = exp2(xe) * max_j (r_j * rd_j) ----------------
// 256 nodes per wave (4 chunks of 64), row-per-lane (60 indep loads/wave-chunk).
__global__ __launch_bounds__(256) void k3_output(
    const float* __restrict__ x, const float* __restrict__ uniforms,
    const int* __restrict__ ptr, const float* __restrict__ rd,
    float* __restrict__ out, int N, int B)
{
    const int wid  = (blockIdx.x << 2) + (threadIdx.x >> 6);
    const int lane = threadIdx.x & 63;
    const int base = wid << 8;  // 256 nodes / wave
    if (base >= N) return;

    const int n0 = base + lane;
    int lo = 0, hi = B;
    while (hi - lo > 1) { int mid = (lo + hi) >> 1; if (ptr[mid] <= n0) lo = mid; else hi = mid; }
    int seg = lo;

    for (int c = 0; c < 4; ++c) {
        const int n = base + (c << 6) + lane;
        if (n >= N) return;
        while (n >= ptr[seg + 1]) ++seg;  // monotone advance, L1-hot

        float l[NK3];
#pragma unroll
        for (int j = 0; j < NK3; ++j) l[j] = rd[seg * NK3 + j];

        const float2* row = reinterpret_cast<const float2*>(uniforms + (size_t)n * NK3);
        float mx = 0.0f;
#pragma unroll
        for (int k = 0; k < NKP; ++k) {
            const float2 u = row[k];
            const float r0 = hw_rcp(-hw_log2(u.x));
            const float r1 = hw_rcp(-hw_log2(u.y));
            mx = fmaxf(mx, fmaxf(r0 * l[2 * k], r1 * l[2 * k + 1]));
        }
        out[n] = hw_exp2(x[n] * 1.44269504f) * mx;
    }
}

// ---------------- Fallback: round-3 single kernel (if ws too small) ----------------
__global__ __launch_bounds__(256) void gnn_fallback(
    const float* __restrict__ x, const float* __restrict__ uniforms,
    const int* __restrict__ ptr, float* __restrict__ out)
{
    const int wave = threadIdx.x >> 6;
    const int lane = threadIdx.x & 63;
    const int g = (blockIdx.x << 2) + wave;
    const int start = ptr[g];
    const int end   = ptr[g + 1];
    if (end <= start) return;

    float acc[NK3];
#pragma unroll
    for (int j = 0; j < NK3; ++j) acc[j] = 0.0f;
    const int iters = (end - start + 63) >> 6;

    for (int it = 0; it < iters; ++it) {
        const int n = start + (it << 6) + lane;
        if (n < end) {
            const float E = hw_exp2(x[n] * 1.44269504f);
            const float2* row = reinterpret_cast<const float2*>(uniforms + (size_t)n * NK3);
#pragma unroll
            for (int k = 0; k < NKP; ++k) {
                float2 u = row[k];
                acc[2 * k]     = fmaf(E, hw_rcp(-hw_log2(u.x)), acc[2 * k]);
                acc[2 * k + 1] = fmaf(E, hw_rcp(-hw_log2(u.y)), acc[2 * k + 1]);
            }
        }
    }
#pragma unroll
    for (int j = 0; j < NK3; ++j) {
        float v = acc[j];
#pragma unroll
        for (int off = 1; off < 64; off <<= 1) v += __shfl_xor(v, off, 64);
        acc[j] = hw_rcp(v);
    }
    for (int it = 0; it < iters; ++it) {
        const int n = start + (it << 6) + lane;
        if (n < end) {
            const float2* row = reinterpret_cast<const float2*>(uniforms + (size_t)n * NK3);
            float mx = 0.0f;
#pragma unroll
            for (int k = 0; k < NKP; ++k) {
                float2 u = row[k];
                const float r0 = hw_rcp(-hw_log2(u.x));
                const float r1 = hw_rcp(-hw_log2(u.y));
                mx = fmaxf(mx, fmaxf(r0 * acc[2 * k], r1 * acc[2 * k + 1]));
            }
            out[n] = hw_exp2(x[n] * 1.44269504f) * mx;
        }
    }
}

extern "C" void kernel_launch(void* const* d_in, const int* in_sizes, int n_in,
                              void* d_out, int out_size, void* d_ws, size_t ws_size,
                              hipStream_t stream) {
    const float* x        = (const float*)d_in[0];
    const float* uniforms = (const float*)d_in[1];
    const int*   ptr      = (const int*)d_in[2];
    float* out = (float*)d_out;

    const int N = in_sizes[0];
    const int B = in_sizes[2] - 1;
    const size_t ws_needed = (size_t)B * NK3 * sizeof(float);

    if (ws_size >= ws_needed && d_ws != nullptr) {
        float* wsum = (float*)d_ws;
        hipMemsetAsync(wsum, 0, ws_needed, stream);

        const int b1 = (N + 511) / 512;           // 4 waves x 128 nodes
        k1_accumulate<<<b1, 256, 0, stream>>>(x, uniforms, ptr, wsum, N, B);

        const int cnt = B * NK3;
        const int b2 = (cnt + 255) / 256;
        k2_rcp<<<b2, 256, 0, stream>>>(wsum, cnt);

        const int b3 = (N + 1023) / 1024;         // 4 waves x 256 nodes
        k3_output<<<b3, 256, 0, stream>>>(x, uniforms, ptr, wsum, out, N, B);
    } else {
        const int blocks = (B + 3) / 4;
        gnn_fallback<<<blocks, 256, 0, stream>>>(x, uniforms, ptr, out);
    }
}

// Round 6
// 81.067 us; speedup vs baseline: 1.0516x; 1.0048x over previous
//
#include <hip/hip_runtime.h>

#define NK3 30  // 3*K columns per node
#define NKP 15  // float2 pairs per row

__device__ __forceinline__ float hw_log2(float a) { return __builtin_amdgcn_logf(a); }
__device__ __forceinline__ float hw_exp2(float a) { return __builtin_amdgcn_exp2f(a); }
__device__ __forceinline__ float hw_rcp(float a)  { return __builtin_amdgcn_rcpf(a); }

// Math: e_nj = exp(x_n + gumbel_nj) = exp(x_n) * 1/(-ln u_nj)
//            = exp2(x_n*log2e) * rcp(-log2 u_nj) * (1/ln2)   [1/ln2 cancels in ratio]
// denom'_j = sum_n exp2(xe_n)*rcp(w_nj);  out = exp2(xe)*max_j(r_j * rcp(denom'_j)).

// ---------------- K0: zero the workspace (replaces slow rocclr fill) ----------------
__global__ __launch_bounds__(256) void k0_zero(float4* __restrict__ ws, int count4)
{
    const int i = blockIdx.x * 256 + threadIdx.x;
    if (i < count4) ws[i] = make_float4(0.f, 0.f, 0.f, 0.f);
}

// ---------------- K1: balanced flat accumulation, deep-MLP ----------------
// 128 nodes per wave. Lane layout: nodesub = lane>>4, cp = lane&15 (15 active
// float2 column-pairs). 4 supersteps x 32 nodes: batch 16 independent loads
// into registers first (MLP=16), then branch logic on registers.
__global__ __launch_bounds__(256) void k1_accumulate(
    const float* __restrict__ x, const float* __restrict__ uniforms,
    const int* __restrict__ ptr, float* __restrict__ wsum, int N, int B)
{
    const int wid  = (blockIdx.x << 2) + (threadIdx.x >> 6);
    const int lane = threadIdx.x & 63;
    const int nodesub = lane >> 4;
    const int cp      = lane & 15;
    const bool active = cp < NKP;
    const int cpl     = active ? cp : 0;   // keep inactive lanes' loads in-bounds

    const int base = wid << 7;  // 128 nodes / wave
    if (base >= N) return;

    const int n0 = base + nodesub;
    int lo = 0, hi = B;  // largest seg with ptr[seg] <= n0
    while (hi - lo > 1) { int mid = (lo + hi) >> 1; if (ptr[mid] <= n0) lo = mid; else hi = mid; }
    int seg = lo;
    int ptr_next = ptr[seg + 1];

    float ax = 0.f, ay = 0.f;

    for (int s8 = 0; s8 < 4; ++s8) {
        float2 u[8];
        float  xv[8];
#pragma unroll
        for (int q = 0; q < 8; ++q) {
            const int n = base + (s8 << 5) + (q << 2) + nodesub;
            const int nc = (n < N) ? n : (N - 1);
            u[q]  = reinterpret_cast<const float2*>(uniforms + (size_t)nc * NK3)[cpl];
            xv[q] = x[nc];
        }
#pragma unroll
        for (int q = 0; q < 8; ++q) {
            const int n = base + (s8 << 5) + (q << 2) + nodesub;
            if (n < N) {
                if (n >= ptr_next) {  // crossed into new segment: flush old acc
                    if (active) {
                        atomicAdd(&wsum[seg * NK3 + (cp << 1)    ], ax);
                        atomicAdd(&wsum[seg * NK3 + (cp << 1) + 1], ay);
                    }
                    ax = 0.f; ay = 0.f;
                    do { ++seg; ptr_next = ptr[seg + 1]; } while (n >= ptr_next);
                }
                const float E  = hw_exp2(xv[q] * 1.44269504f);
                const float w0 = -hw_log2(u[q].x);
                const float w1 = -hw_log2(u[q].y);
                ax = fmaf(E, hw_rcp(w0), ax);
                ay = fmaf(E, hw_rcp(w1), ay);
            }
        }
    }
    if (active) {
        atomicAdd(&wsum[seg * NK3 + (cp << 1)    ], ax);
        atomicAdd(&wsum[seg * NK3 + (cp << 1) + 1], ay);
    }
}

// ---------------- K2: rd = rcp(denom'), in place ----------------
__global__ __launch_bounds__(256) void k2_rcp(float* __restrict__ wsum, int count)
{
    const int i = blockIdx.x * 256 + threadIdx.x;
    if (i < count) wsum[i] = hw_rcp(wsum[i]);
}

// ---------------- K3: out[n] = exp2(xe) * max_j (r_j * rd_j) ----------------
// 256 nodes per wave (4 chunks of 64), row-per-lane (60 indep loads/wave-chunk).
__global__ __launch_bounds__(256) void k3_output(
    const float* __restrict__ x, const float* __restrict__ uniforms,
    const int* __restrict__ ptr, const float* __restrict__ rd,
    float* __restrict__ out, int N, int B)
{
    const int wid  = (blockIdx.x << 2) + (threadIdx.x >> 6);
    const int lane = threadIdx.x & 63;
    const int base = wid << 8;  // 256 nodes / wave
    if (base >= N) return;

    const int n0 = base + lane;
    int lo = 0, hi = B;
    while (hi - lo > 1) { int mid = (lo + hi) >> 1; if (ptr[mid] <= n0) lo = mid; else hi = mid; }
    int seg = lo;

    for (int c = 0; c < 4; ++c) {
        const int n = base + (c << 6) + lane;
        if (n >= N) return;
        while (n >= ptr[seg + 1]) ++seg;  // monotone advance, L1-hot

        float l[NK3];
#pragma unroll
        for (int j = 0; j < NK3; ++j) l[j] = rd[seg * NK3 + j];

        const float2* row = reinterpret_cast<const float2*>(uniforms + (size_t)n * NK3);
        float mx = 0.0f;
#pragma unroll
        for (int k = 0; k < NKP; ++k) {
            const float2 u = row[k];
            const float r0 = hw_rcp(-hw_log2(u.x));
            const float r1 = hw_rcp(-hw_log2(u.y));
            mx = fmaxf(mx, fmaxf(r0 * l[2 * k], r1 * l[2 * k + 1]));
        }
        out[n] = hw_exp2(x[n] * 1.44269504f) * mx;
    }
}

// ---------------- Fallback: single kernel (if ws too small) ----------------
__global__ __launch_bounds__(256) void gnn_fallback(
    const float* __restrict__ x, const float* __restrict__ uniforms,
    const int* __restrict__ ptr, float* __restrict__ out)
{
    const int wave = threadIdx.x >> 6;
    const int lane = threadIdx.x & 63;
    const int g = (blockIdx.x << 2) + wave;
    const int start = ptr[g];
    const int end   = ptr[g + 1];
    if (end <= start) return;

    float acc[NK3];
#pragma unroll
    for (int j = 0; j < NK3; ++j) acc[j] = 0.0f;
    const int iters = (end - start + 63) >> 6;

    for (int it = 0; it < iters; ++it) {
        const int n = start + (it << 6) + lane;
        if (n < end) {
            const float E = hw_exp2(x[n] * 1.44269504f);
            const float2* row = reinterpret_cast<const float2*>(uniforms + (size_t)n * NK3);
#pragma unroll
            for (int k = 0; k < NKP; ++k) {
                float2 u = row[k];
                acc[2 * k]     = fmaf(E, hw_rcp(-hw_log2(u.x)), acc[2 * k]);
                acc[2 * k + 1] = fmaf(E, hw_rcp(-hw_log2(u.y)), acc[2 * k + 1]);
            }
        }
    }
#pragma unroll
    for (int j = 0; j < NK3; ++j) {
        float v = acc[j];
#pragma unroll
        for (int off = 1; off < 64; off <<= 1) v += __shfl_xor(v, off, 64);
        acc[j] = hw_rcp(v);
    }
    for (int it = 0; it < iters; ++it) {
        const int n = start + (it << 6) + lane;
        if (n < end) {
            const float2* row = reinterpret_cast<const float2*>(uniforms + (size_t)n * NK3);
            float mx = 0.0f;
#pragma unroll
            for (int k = 0; k < NKP; ++k) {
                float2 u = row[k];
                const float r0 = hw_rcp(-hw_log2(u.x));
                const float r1 = hw_rcp(-hw_log2(u.y));
                mx = fmaxf(mx, fmaxf(r0 * acc[2 * k], r1 * acc[2 * k + 1]));
            }
            out[n] = hw_exp2(x[n] * 1.44269504f) * mx;
        }
    }
}

extern "C" void kernel_launch(void* const* d_in, const int* in_sizes, int n_in,
                              void* d_out, int out_size, void* d_ws, size_t ws_size,
                              hipStream_t stream) {
    const float* x        = (const float*)d_in[0];
    const float* uniforms = (const float*)d_in[1];
    const int*   ptr      = (const int*)d_in[2];
    float* out = (float*)d_out;

    const int N = in_sizes[0];
    const int B = in_sizes[2] - 1;
    const size_t ws_needed = (size_t)B * NK3 * sizeof(float);

    if (ws_size >= ws_needed && d_ws != nullptr) {
        float* wsum = (float*)d_ws;

        const int cnt  = B * NK3;            // 122880 floats
        const int cnt4 = cnt >> 2;           // exact: B*NK3 % 4 == 0 for B mult of 2
        const int b0 = (cnt4 + 255) / 256;
        k0_zero<<<b0, 256, 0, stream>>>((float4*)wsum, cnt4);

        const int b1 = (N + 511) / 512;      // 4 waves x 128 nodes
        k1_accumulate<<<b1, 256, 0, stream>>>(x, uniforms, ptr, wsum, N, B);

        const int b2 = (cnt + 255) / 256;
        k2_rcp<<<b2, 256, 0, stream>>>(wsum, cnt);

        const int b3 = (N + 1023) / 1024;    // 4 waves x 256 nodes
        k3_output<<<b3, 256, 0, stream>>>(x, uniforms, ptr, wsum, out, N, B);
    } else {
        const int blocks = (B + 3) / 4;
        gnn_fallback<<<blocks, 256, 0, stream>>>(x, uniforms, ptr, out);
    }
}